// Round 10
// baseline (2025.846 us; speedup 1.0000x reference)
//
#include <hip/hip_runtime.h>
#include <hip/hip_bf16.h>
#include <cstddef>

#define HW 4096   // 64*64

// ---------------------------------------------------------------------------
// N1: raw projection. grid (4096 pixels, 6 images), thread = out channel.
//   img 0: q = x[0] @ Wq^T + bq ; img 1..5: s[k] = x[k] @ Ws^T + bs
// ---------------------------------------------------------------------------
__global__ __launch_bounds__(256) void n_proj(
    const float* __restrict__ x, const float* __restrict__ Wq, const float* __restrict__ bq,
    const float* __restrict__ Ws, const float* __restrict__ bs, float* __restrict__ qs) {
  const int p = blockIdx.x;
  const int n = blockIdx.y;
  const int c = threadIdx.x;
  const float* __restrict__ W = (n == 0) ? Wq : Ws;
  const float* __restrict__ B = (n == 0) ? bq : bs;
  float dot = B[c];
  for (int ci = 0; ci < 256; ++ci)
    dot += x[((size_t)n * 256 + ci) * HW + p] * W[c * 256 + ci];
  qs[((size_t)n * HW + p) * 256 + c] = dot;
}

// ---------------------------------------------------------------------------
// N2: in-place per-(pixel, head) l2norm; img 0 additionally * scale * 32^-0.5
// ---------------------------------------------------------------------------
__global__ __launch_bounds__(256) void n_norm(const float* __restrict__ scale,
                                              float* __restrict__ qs) {
  const int p = blockIdx.x;
  const int n = blockIdx.y;
  const int c = threadIdx.x;
  const int h = c >> 5;
  const size_t base = ((size_t)n * HW + p) * 256;
  float v = qs[base + c];
  float ss = 0.f;
  for (int d = 0; d < 32; ++d) {
    float u = qs[base + h * 32 + d];
    ss += u * u;
  }
  __syncthreads();                     // all reads complete before in-place writes
  float r = v / fmaxf(sqrtf(ss), 1e-12f);
  if (n == 0) r *= scale[0] * 0.17677669529663687f;   // scale * HD^-0.5
  qs[base + c] = r;
}

// ---------------------------------------------------------------------------
// N3a: raw patch aggregation + mask. grid (256 patches, 5 masks), thread (h,d).
//   patch s=(y/4)*16+(x/4), cell l=(y%4)*4+(x%4); delta nearest at (8y,8x).
// ---------------------------------------------------------------------------
__global__ __launch_bounds__(256) void n_agg(
    const float* __restrict__ delta, const float* __restrict__ qs,
    float* __restrict__ cf, float* __restrict__ cb, float* __restrict__ mask) {
  const int s = blockIdx.x;
  const int k = blockIdx.y;
  const int t = threadIdx.x, h = t >> 5, d = t & 31;
  const float* __restrict__ s_n = qs + (size_t)(k + 1) * (256 * HW);
  float af = 0.f, ab = 0.f;
  for (int l = 0; l < 16; ++l) {
    int y = (s >> 4) * 4 + (l >> 2);
    int xx = (s & 15) * 4 + (l & 3);
    float f = delta[(size_t)k * 262144 + (size_t)(y * 8) * 512 + xx * 8];
    float sv = s_n[(size_t)(y * 64 + xx) * 256 + h * 32 + d];
    af += f * sv;
    ab += (1.f - f) * sv;
  }
  cf[(((size_t)k * 256 + s) * 8 + h) * 32 + d] = af;
  cb[(((size_t)k * 256 + s) * 8 + h) * 32 + d] = ab;
  if (t == 0) {
    float fs = 0.f;
    for (int l = 0; l < 16; ++l) {
      int y = (s >> 4) * 4 + (l >> 2);
      int xx = (s & 15) * 4 + (l & 3);
      fs += delta[(size_t)k * 262144 + (size_t)(y * 8) * 512 + xx * 8];
    }
    mask[k * 512 + s]       = (fs < 1.f) ? -1e30f : 0.f;          // fg
    mask[k * 512 + 256 + s] = ((16.f - fs) < 1.f) ? -1e30f : 0.f; // bg
  }
}

// ---------------------------------------------------------------------------
// N3b: l2norm prototypes -> c_s[h][j][d], j = k*512 + {s | 256+s}
// ---------------------------------------------------------------------------
__global__ __launch_bounds__(256) void n_csnorm(
    const float* __restrict__ cf, const float* __restrict__ cb, float* __restrict__ c_s) {
  const int s = blockIdx.x;
  const int k = blockIdx.y;
  const int t = threadIdx.x, h = t >> 5, d = t & 31;
  const size_t ib = (((size_t)k * 256 + s) * 8 + h) * 32;
  float sf = 0.f, sb = 0.f;
  for (int d2 = 0; d2 < 32; ++d2) {
    float a = cf[ib + d2], b = cb[ib + d2];
    sf += a * a;
    sb += b * b;
  }
  c_s[((size_t)h * 2560 + k * 512 + s) * 32 + d]       = cf[ib + d] / fmaxf(sqrtf(sf), 1e-12f);
  c_s[((size_t)h * 2560 + k * 512 + 256 + s) * 32 + d] = cb[ib + d] / fmaxf(sqrtf(sb), 1e-12f);
}

// ---------------------------------------------------------------------------
// N4: attention. grid (16, 8 heads), thread = pixel. xo = fg attn mass.
// ---------------------------------------------------------------------------
__global__ __launch_bounds__(256) void n_attn(
    const float* __restrict__ qs, const float* __restrict__ c_s,
    const float* __restrict__ mask, float* __restrict__ xo) {
  const int p = blockIdx.x * 256 + threadIdx.x;
  const int h = blockIdx.y;
  float qv[32];
  for (int d = 0; d < 32; ++d) qv[d] = qs[(size_t)p * 256 + h * 32 + d];
  float num = 0.f, den = 0.f;
  for (int j = 0; j < 2560; ++j) {
    float dot = 0.f;
    for (int d = 0; d < 32; ++d) dot += qv[d] * c_s[((size_t)h * 2560 + j) * 32 + d];
    float e = __expf(dot + mask[j]);   // masked -> exp(-1e30) = 0
    den += e;
    if ((j & 511) < 256) num += e;     // j%512 < 256 -> fg key
  }
  xo[(size_t)h * HW + p] = num / den;
}

// ---------------------------------------------------------------------------
// N5: conv (cross-correlation, as lax.conv_general_dilated — NO kernel flip)
// ---------------------------------------------------------------------------
template <int CI, int KS, int PAD>
__global__ __launch_bounds__(256) void n_conv(
    const float* __restrict__ in, const float* __restrict__ w,
    const float* __restrict__ b, float* __restrict__ out) {
  const int co = blockIdx.y;
  const int p = blockIdx.x * 256 + threadIdx.x;
  const int y = p >> 6, xx = p & 63;
  float acc = b[co];
  for (int ci = 0; ci < CI; ++ci)
    for (int ky = 0; ky < KS; ++ky) {
      int iy = y + ky - PAD;
      if (iy < 0 || iy >= 64) continue;
      for (int kx = 0; kx < KS; ++kx) {
        int ix = xx + kx - PAD;
        if (ix < 0 || ix >= 64) continue;
        acc += in[(size_t)ci * HW + iy * 64 + ix] *
               w[(size_t)((co * CI + ci) * KS + ky) * KS + kx];
      }
    }
  out[(size_t)co * HW + p] = acc;
}

// ---------------------------------------------------------------------------
// N6: GroupNorm stats (shared-array tree reduction)
// ---------------------------------------------------------------------------
__global__ __launch_bounds__(256) void n_gnstats(const float* __restrict__ in,
                                                 float* __restrict__ st, int cpg) {
  __shared__ float sh[256], sh2[256];
  const int g = blockIdx.x, t = threadIdx.x;
  const int n = cpg * HW;
  const float* __restrict__ base = in + (size_t)g * n;
  float s = 0.f, ss = 0.f;
  for (int i = t; i < n; i += 256) {
    float v = base[i];
    s += v;
    ss += v * v;
  }
  sh[t] = s; sh2[t] = ss;
  __syncthreads();
  for (int w = 128; w > 0; w >>= 1) {
    if (t < w) { sh[t] += sh[t + w]; sh2[t] += sh2[t + w]; }
    __syncthreads();
  }
  if (t == 0) {
    float mean = sh[0] / n;
    float var = sh2[0] / n - mean * mean;
    st[g * 2] = mean;
    st[g * 2 + 1] = 1.0f / sqrtf(var + 1e-5f);
  }
}

// ---------------------------------------------------------------------------
// N7: GroupNorm apply + ReLU. OUTPUT IS FLOAT32 (reference output dtype).
// ---------------------------------------------------------------------------
__global__ __launch_bounds__(256) void n_gnapply(
    const float* __restrict__ in, float* __restrict__ out, const float* __restrict__ st,
    const float* __restrict__ gs, const float* __restrict__ gb, int cpg) {
  const int idx = blockIdx.x * 256 + threadIdx.x;
  const int c = idx >> 12;
  const int g = c / cpg;
  float v = (in[idx] - st[g * 2]) * st[g * 2 + 1] * gs[c] + gb[c];
  out[idx] = fmaxf(v, 0.f);
}

// ---------------------------------------------------------------------------
extern "C" void kernel_launch(void* const* d_in, const int* in_sizes, int n_in,
                              void* d_out, int out_size, void* d_ws, size_t ws_size,
                              hipStream_t stream) {
  const float* x     = (const float*)d_in[0];
  const float* delta = (const float*)d_in[1];
  const float* Wq    = (const float*)d_in[2];
  const float* bq    = (const float*)d_in[3];
  const float* Ws    = (const float*)d_in[4];
  const float* bs    = (const float*)d_in[5];
  const float* scale = (const float*)d_in[6];
  const float* c1w = (const float*)d_in[7],  *c1b = (const float*)d_in[8];
  const float* g1s = (const float*)d_in[9],  *g1b = (const float*)d_in[10];
  const float* c2w = (const float*)d_in[11], *c2b = (const float*)d_in[12];
  const float* g2s = (const float*)d_in[13], *g2b = (const float*)d_in[14];
  const float* c3w = (const float*)d_in[15], *c3b = (const float*)d_in[16];
  const float* g3s = (const float*)d_in[17], *g3b = (const float*)d_in[18];

  float* ws   = (float*)d_ws;
  float* qs   = ws;                       // 6*4096*256 = 6,291,456 (raw->normed in place)
  float* c_s  = qs + 6291456;             // 8*2560*32  =   655,360
  float* mask = c_s + 655360;             //                  2,560
  float* xo   = mask + 2560;              //                 32,768
  float* st   = xo + 32768;               //                     32 (24 used)
  float* un   = st + 32;                  // union region, 1,179,648 floats
  // phase 1 (before convs): cf, cb
  float* cf   = un;                       //   327,680
  float* cb   = un + 327680;              //   327,680
  // phase 2 (after attention): conv/GN temporaries
  float* t1   = un;                       //    65,536
  float* a1   = un + 65536;               //    65,536
  float* t2   = un + 131072;              //   262,144
  float* a2   = un + 393216;              //   262,144
  float* t3   = un + 655360;              //   524,288

  n_proj<<<dim3(4096, 6), 256, 0, stream>>>(x, Wq, bq, Ws, bs, qs);
  n_norm<<<dim3(4096, 6), 256, 0, stream>>>(scale, qs);
  n_agg<<<dim3(256, 5), 256, 0, stream>>>(delta, qs, cf, cb, mask);
  n_csnorm<<<dim3(256, 5), 256, 0, stream>>>(cf, cb, c_s);
  n_attn<<<dim3(16, 8), 256, 0, stream>>>(qs, c_s, mask, xo);

  n_conv<8, 5, 2><<<dim3(16, 16), 256, 0, stream>>>(xo, c1w, c1b, t1);
  n_gnstats<<<4, 256, 0, stream>>>(t1, st, 4);
  n_gnapply<<<256, 256, 0, stream>>>(t1, a1, st, g1s, g1b, 4);

  n_conv<16, 3, 1><<<dim3(16, 64), 256, 0, stream>>>(a1, c2w, c2b, t2);
  n_gnstats<<<4, 256, 0, stream>>>(t2, st + 8, 16);
  n_gnapply<<<1024, 256, 0, stream>>>(t2, a2, st + 8, g2s, g2b, 16);

  n_conv<64, 3, 1><<<dim3(16, 128), 256, 0, stream>>>(a2, c3w, c3b, t3);
  n_gnstats<<<4, 256, 0, stream>>>(t3, st + 16, 32);
  n_gnapply<<<2048, 256, 0, stream>>>(t3, (float*)d_out, st + 16, g3s, g3b, 32);
}

// Round 11
// 458.819 us; speedup vs baseline: 4.4154x; 4.4154x over previous
//
#include <hip/hip_runtime.h>
#include <hip/hip_bf16.h>
#include <cstddef>

#define HW 4096   // 64*64

// ---------------------------------------------------------------------------
// Tiled projection + fused per-head l2norm (probe2-verified design, round 6).
// grid (64 pixel-tiles, 6 images), block 256 (thread = out channel).
// q_n[pixel][256]; s_n[k][pixel][256]
// ---------------------------------------------------------------------------
__global__ __launch_bounds__(256) void proj_kernel(
    const float* __restrict__ x, const float* __restrict__ Wq, const float* __restrict__ bq,
    const float* __restrict__ Ws, const float* __restrict__ bs, const float* __restrict__ scale,
    float* __restrict__ q_n, float* __restrict__ s_n) {
  const int n = blockIdx.y;
  const int p0 = blockIdx.x * 64;
  const int t = threadIdx.x;
  const float* __restrict__ W = (n == 0) ? Wq : Ws;
  const float* __restrict__ B = (n == 0) ? bq : bs;

  __shared__ float Wl[256][17];
  __shared__ float Xl[16][64];

  float4 acc[16];
#pragma unroll
  for (int i = 0; i < 16; ++i) acc[i] = make_float4(0.f, 0.f, 0.f, 0.f);

  for (int cc = 0; cc < 256; cc += 16) {
    __syncthreads();
#pragma unroll
    for (int i = 0; i < 16; ++i) {
      int co = i * 16 + (t >> 4), ci = t & 15;
      Wl[co][ci] = W[(size_t)co * 256 + cc + ci];
    }
#pragma unroll
    for (int i = 0; i < 4; ++i) {
      int ci = i * 4 + (t >> 6), p = t & 63;
      Xl[ci][p] = x[(size_t)n * 256 * HW + (size_t)(cc + ci) * HW + p0 + p];
    }
    __syncthreads();
    for (int ci = 0; ci < 16; ++ci) {
      float w = Wl[t][ci];
#pragma unroll
      for (int i = 0; i < 16; ++i) {
        float4 xv = *(const float4*)&Xl[ci][i * 4];
        acc[i].x += w * xv.x; acc[i].y += w * xv.y;
        acc[i].z += w * xv.z; acc[i].w += w * xv.w;
      }
    }
  }

  const float bias = B[t];
  const float qs = scale[0] * 0.17677669529663687f;   // scale * HD^-0.5
  float* __restrict__ outp = (n == 0) ? q_n : (s_n + (size_t)(n - 1) * HW * 256);
#pragma unroll
  for (int i = 0; i < 16; ++i) {
    float vv[4] = {acc[i].x, acc[i].y, acc[i].z, acc[i].w};
#pragma unroll
    for (int u = 0; u < 4; ++u) {
      float v = vv[u] + bias;
      float ss = v * v;
      ss += __shfl_xor(ss, 1);
      ss += __shfl_xor(ss, 2);
      ss += __shfl_xor(ss, 4);
      ss += __shfl_xor(ss, 8);
      ss += __shfl_xor(ss, 16);          // 32-lane head group
      v /= fmaxf(sqrtf(ss), 1e-12f);
      if (n == 0) v *= qs;
      outp[(size_t)(p0 + i * 4 + u) * 256 + t] = v;
    }
  }
}

// ---------------------------------------------------------------------------
// Patch aggregation -> c_s[8][2560][32], mask[2560] (probe2-verified).
// ---------------------------------------------------------------------------
__global__ __launch_bounds__(256) void agg_kernel(
    const float* __restrict__ delta, const float* __restrict__ s_n,
    float* __restrict__ c_s, float* __restrict__ mask) {
  const int s = blockIdx.x;
  const int k = blockIdx.y;
  const int t = threadIdx.x;
  __shared__ float fgl[16];
  const int sy = (s >> 4) * 4, sx = (s & 15) * 4;
  if (t < 16) {
    int y0 = (sy + (t >> 2)) * 8, x0 = (sx + (t & 3)) * 8;
    fgl[t] = delta[(size_t)k * 512 * 512 + (size_t)y0 * 512 + x0];
  }
  __syncthreads();
  const int h = t >> 5, d = t & 31;
  float af = 0.f, ab = 0.f;
#pragma unroll
  for (int l = 0; l < 16; ++l) {
    int pix = (sy + (l >> 2)) * 64 + sx + (l & 3);
    float sv = s_n[((size_t)k * HW + pix) * 256 + h * 32 + d];
    float f = fgl[l];
    af += f * sv;
    ab += (1.f - f) * sv;
  }
  float ssf = af * af, ssb = ab * ab;
#pragma unroll
  for (int m = 1; m <= 16; m <<= 1) {
    ssf += __shfl_xor(ssf, m);
    ssb += __shfl_xor(ssb, m);
  }
  float vf = af / fmaxf(sqrtf(ssf), 1e-12f);
  float vb = ab / fmaxf(sqrtf(ssb), 1e-12f);
  const int jf = k * 512 + s, jb = jf + 256;
  c_s[((size_t)h * 2560 + jf) * 32 + d] = vf;
  c_s[((size_t)h * 2560 + jb) * 32 + d] = vb;
  if (t == 0) {
    float fs = 0.f;
#pragma unroll
    for (int l = 0; l < 16; ++l) fs += fgl[l];
    mask[jf] = (fs < 1.f) ? -1e30f : 0.f;
    mask[jb] = ((16.f - fs) < 1.f) ? -1e30f : 0.f;
  }
}

// ---------------------------------------------------------------------------
// Attention partials: grid (16 pixel-tiles, 8 heads, 10 key-tiles), block 256.
// Each block stages 256 keys (32.8 KB LDS); thread = pixel.
// part[((z*8+h)*HW+p)*2 + {num,den}]
// ---------------------------------------------------------------------------
__global__ __launch_bounds__(256) void attn_kernel(
    const float* __restrict__ q_n, const float* __restrict__ c_s,
    const float* __restrict__ mask, float* __restrict__ part) {
  const int t = threadIdx.x;
  const int p = blockIdx.x * 256 + t;
  const int h = blockIdx.y;
  const int z = blockIdx.z;          // key tile
  __shared__ float csl[256 * 32];
  __shared__ float ml[256];
  const int j0 = z * 256;

#pragma unroll
  for (int i = 0; i < 8; ++i) {
    int idx = i * 256 + t;           // 2048 float4s = 256 keys * 8
    int key = idx >> 3, d4 = idx & 7;
    *(float4*)&csl[idx * 4] =
        *(const float4*)&c_s[((size_t)h * 2560 + j0 + key) * 32 + d4 * 4];
  }
  ml[t] = mask[j0 + t];

  float qv[32];
#pragma unroll
  for (int i = 0; i < 8; ++i) {
    float4 v = *(const float4*)&q_n[(size_t)p * 256 + h * 32 + i * 4];
    qv[i * 4 + 0] = v.x; qv[i * 4 + 1] = v.y; qv[i * 4 + 2] = v.z; qv[i * 4 + 3] = v.w;
  }
  __syncthreads();

  const float cv = ((j0 & 511) < 256) ? 1.f : 0.f;  // whole 256-tile is fg or bg
  float num = 0.f, den = 0.f;
  for (int jj = 0; jj < 256; ++jj) {
    float dot = 0.f;
#pragma unroll
    for (int i = 0; i < 8; ++i) {
      float4 c4 = *(const float4*)&csl[jj * 32 + i * 4];
      dot += qv[i * 4 + 0] * c4.x + qv[i * 4 + 1] * c4.y +
             qv[i * 4 + 2] * c4.z + qv[i * 4 + 3] * c4.w;
    }
    float e = __expf(dot + ml[jj]);   // masked -> 0
    den += e;
    num += cv * e;
  }
  float* o = &part[(((size_t)z * 8 + h) * HW + p) * 2];
  o[0] = num;
  o[1] = den;
}

// merge 10 key-tile partials: xo[h*HW+p]
__global__ __launch_bounds__(256) void merge_kernel(const float* __restrict__ part,
                                                    float* __restrict__ xo) {
  int idx = blockIdx.x * 256 + threadIdx.x;   // 32768 = h*HW+p
  int h = idx >> 12, p = idx & 4095;
  float n = 0.f, d = 0.f;
#pragma unroll
  for (int z = 0; z < 10; ++z) {
    const float* o = &part[(((size_t)z * 8 + h) * HW + p) * 2];
    n += o[0];
    d += o[1];
  }
  xo[idx] = n / d;
}

// ---------------------------------------------------------------------------
// Conv (cross-correlation) — naive; weight index uniform per block (scalarized)
// ---------------------------------------------------------------------------
template <int CI, int KS, int PAD>
__global__ __launch_bounds__(256) void n_conv(
    const float* __restrict__ in, const float* __restrict__ w,
    const float* __restrict__ b, float* __restrict__ out) {
  const int co = blockIdx.y;
  const int p = blockIdx.x * 256 + threadIdx.x;
  const int y = p >> 6, xx = p & 63;
  float acc = b[co];
  for (int ci = 0; ci < CI; ++ci)
#pragma unroll
    for (int ky = 0; ky < KS; ++ky) {
      int iy = y + ky - PAD;
      if (iy < 0 || iy >= 64) continue;
#pragma unroll
      for (int kx = 0; kx < KS; ++kx) {
        int ix = xx + kx - PAD;
        if (ix < 0 || ix >= 64) continue;
        acc += in[(size_t)ci * HW + iy * 64 + ix] *
               w[(size_t)((co * CI + ci) * KS + ky) * KS + kx];
      }
    }
  out[(size_t)co * HW + p] = acc;
}

// ---------------------------------------------------------------------------
// GroupNorm stats, two-stage: A = 16 partial blocks per group, B = finalize.
// ---------------------------------------------------------------------------
__global__ __launch_bounds__(256) void gnstatsA(const float* __restrict__ in,
                                                float* __restrict__ stp, int cpg) {
  __shared__ float sh[256], sh2[256];
  const int g = blockIdx.x, b = blockIdx.y, t = threadIdx.x;
  const int n = cpg * HW;
  const int chunk = n >> 4;
  const float* __restrict__ base = in + (size_t)g * n + (size_t)b * chunk;
  float s = 0.f, ss = 0.f;
  for (int i = t; i < chunk; i += 256) {
    float v = base[i];
    s += v;
    ss += v * v;
  }
  sh[t] = s; sh2[t] = ss;
  __syncthreads();
  for (int w = 128; w > 0; w >>= 1) {
    if (t < w) { sh[t] += sh[t + w]; sh2[t] += sh2[t + w]; }
    __syncthreads();
  }
  if (t == 0) { stp[(g * 16 + b) * 2] = sh[0]; stp[(g * 16 + b) * 2 + 1] = sh2[0]; }
}

__global__ __launch_bounds__(64) void gnstatsB(const float* __restrict__ stp,
                                               float* __restrict__ st, int cpg) {
  const int g = blockIdx.x;
  if (threadIdx.x == 0) {
    float S = 0.f, SS = 0.f;
    for (int b = 0; b < 16; ++b) { S += stp[(g * 16 + b) * 2]; SS += stp[(g * 16 + b) * 2 + 1]; }
    float n = (float)(cpg * HW);
    float mean = S / n;
    float var = SS / n - mean * mean;
    st[g * 2] = mean;
    st[g * 2 + 1] = 1.0f / sqrtf(var + 1e-5f);
  }
}

// GroupNorm apply + ReLU, float32 out (reference output dtype).
__global__ __launch_bounds__(256) void gn_apply(
    const float* __restrict__ in, float* __restrict__ out, const float* __restrict__ st,
    const float* __restrict__ gs, const float* __restrict__ gb, int cpg) {
  const int idx = blockIdx.x * 256 + threadIdx.x;
  const int c = idx >> 12;
  const int g = c / cpg;
  float v = (in[idx] - st[g * 2]) * st[g * 2 + 1] * gs[c] + gb[c];
  out[idx] = fmaxf(v, 0.f);
}

// ---------------------------------------------------------------------------
extern "C" void kernel_launch(void* const* d_in, const int* in_sizes, int n_in,
                              void* d_out, int out_size, void* d_ws, size_t ws_size,
                              hipStream_t stream) {
  const float* x     = (const float*)d_in[0];
  const float* delta = (const float*)d_in[1];
  const float* Wq    = (const float*)d_in[2];
  const float* bq    = (const float*)d_in[3];
  const float* Ws    = (const float*)d_in[4];
  const float* bs    = (const float*)d_in[5];
  const float* scale = (const float*)d_in[6];
  const float* c1w = (const float*)d_in[7],  *c1b = (const float*)d_in[8];
  const float* g1s = (const float*)d_in[9],  *g1b = (const float*)d_in[10];
  const float* c2w = (const float*)d_in[11], *c2b = (const float*)d_in[12];
  const float* g2s = (const float*)d_in[13], *g2b = (const float*)d_in[14];
  const float* c3w = (const float*)d_in[15], *c3b = (const float*)d_in[16];
  const float* g3s = (const float*)d_in[17], *g3b = (const float*)d_in[18];

  float* ws   = (float*)d_ws;
  float* q_n  = ws;                       // 1,048,576
  float* s_n  = q_n + 1048576;            // 5,242,880
  float* c_s  = s_n + 5242880;            //   655,360
  float* mask = c_s + 655360;             //     2,560
  float* xo   = mask + 2560;              //    32,768
  float* st   = xo + 32768;               //        32
  float* stp  = st + 32;                  //       512 (128 used)
  float* un   = stp + 512;                // union: part (655,360) then conv temps
  float* part = un;                       //   655,360 (10*8*4096*2)
  float* t1   = un;                       //    65,536
  float* a1   = un + 65536;               //    65,536
  float* t2   = un + 131072;              //   262,144
  float* a2   = un + 393216;              //   262,144
  float* t3   = un + 655360;              //   524,288
  // total: 6,982,720 + 1,179,648 = 8,162,368 floats ~= 32.6 MB

  proj_kernel<<<dim3(64, 6), 256, 0, stream>>>(x, Wq, bq, Ws, bs, scale, q_n, s_n);
  agg_kernel<<<dim3(256, 5), 256, 0, stream>>>(delta, s_n, c_s, mask);
  attn_kernel<<<dim3(16, 8, 10), 256, 0, stream>>>(q_n, c_s, mask, part);
  merge_kernel<<<128, 256, 0, stream>>>(part, xo);

  n_conv<8, 5, 2><<<dim3(16, 16), 256, 0, stream>>>(xo, c1w, c1b, t1);
  gnstatsA<<<dim3(4, 16), 256, 0, stream>>>(t1, stp, 4);
  gnstatsB<<<4, 64, 0, stream>>>(stp, st, 4);
  gn_apply<<<256, 256, 0, stream>>>(t1, a1, st, g1s, g1b, 4);

  n_conv<16, 3, 1><<<dim3(16, 64), 256, 0, stream>>>(a1, c2w, c2b, t2);
  gnstatsA<<<dim3(4, 16), 256, 0, stream>>>(t2, stp + 128, 16);
  gnstatsB<<<4, 64, 0, stream>>>(stp + 128, st + 8, 16);
  gn_apply<<<1024, 256, 0, stream>>>(t2, a2, st + 8, g2s, g2b, 16);

  n_conv<64, 3, 1><<<dim3(16, 128), 256, 0, stream>>>(a2, c3w, c3b, t3);
  gnstatsA<<<dim3(4, 16), 256, 0, stream>>>(t3, stp + 256, 32);
  gnstatsB<<<4, 64, 0, stream>>>(stp + 256, st + 16, 32);
  gn_apply<<<2048, 256, 0, stream>>>(t3, (float*)d_out, st + 16, g3s, g3b, 32);
}

// Round 12
// 457.464 us; speedup vs baseline: 4.4284x; 1.0030x over previous
//
#include <hip/hip_runtime.h>
#include <hip/hip_bf16.h>
#include <cstddef>

#define HW 4096   // 64*64

// ---------------------------------------------------------------------------
// Tiled projection + fused per-head l2norm (probe2-verified design, round 6).
// grid (64 pixel-tiles, 6 images), block 256 (thread = out channel).
// q_n[pixel][256]; s_n[k][pixel][256]
// ---------------------------------------------------------------------------
__global__ __launch_bounds__(256) void proj_kernel(
    const float* __restrict__ x, const float* __restrict__ Wq, const float* __restrict__ bq,
    const float* __restrict__ Ws, const float* __restrict__ bs, const float* __restrict__ scale,
    float* __restrict__ q_n, float* __restrict__ s_n) {
  const int n = blockIdx.y;
  const int p0 = blockIdx.x * 64;
  const int t = threadIdx.x;
  const float* __restrict__ W = (n == 0) ? Wq : Ws;
  const float* __restrict__ B = (n == 0) ? bq : bs;

  __shared__ float Wl[256][17];
  __shared__ float Xl[16][64];

  float4 acc[16];
#pragma unroll
  for (int i = 0; i < 16; ++i) acc[i] = make_float4(0.f, 0.f, 0.f, 0.f);

  for (int cc = 0; cc < 256; cc += 16) {
    __syncthreads();
#pragma unroll
    for (int i = 0; i < 16; ++i) {
      int co = i * 16 + (t >> 4), ci = t & 15;
      Wl[co][ci] = W[(size_t)co * 256 + cc + ci];
    }
#pragma unroll
    for (int i = 0; i < 4; ++i) {
      int ci = i * 4 + (t >> 6), p = t & 63;
      Xl[ci][p] = x[(size_t)n * 256 * HW + (size_t)(cc + ci) * HW + p0 + p];
    }
    __syncthreads();
    for (int ci = 0; ci < 16; ++ci) {
      float w = Wl[t][ci];
#pragma unroll
      for (int i = 0; i < 16; ++i) {
        float4 xv = *(const float4*)&Xl[ci][i * 4];
        acc[i].x += w * xv.x; acc[i].y += w * xv.y;
        acc[i].z += w * xv.z; acc[i].w += w * xv.w;
      }
    }
  }

  const float bias = B[t];
  const float qs = scale[0] * 0.17677669529663687f;   // scale * HD^-0.5
  float* __restrict__ outp = (n == 0) ? q_n : (s_n + (size_t)(n - 1) * HW * 256);
#pragma unroll
  for (int i = 0; i < 16; ++i) {
    float vv[4] = {acc[i].x, acc[i].y, acc[i].z, acc[i].w};
#pragma unroll
    for (int u = 0; u < 4; ++u) {
      float v = vv[u] + bias;
      float ss = v * v;
      ss += __shfl_xor(ss, 1);
      ss += __shfl_xor(ss, 2);
      ss += __shfl_xor(ss, 4);
      ss += __shfl_xor(ss, 8);
      ss += __shfl_xor(ss, 16);          // 32-lane head group
      v /= fmaxf(sqrtf(ss), 1e-12f);
      if (n == 0) v *= qs;
      outp[(size_t)(p0 + i * 4 + u) * 256 + t] = v;
    }
  }
}

// ---------------------------------------------------------------------------
// Patch aggregation -> c_s[8][2560][32], mask[2560] (probe2-verified).
// ---------------------------------------------------------------------------
__global__ __launch_bounds__(256) void agg_kernel(
    const float* __restrict__ delta, const float* __restrict__ s_n,
    float* __restrict__ c_s, float* __restrict__ mask) {
  const int s = blockIdx.x;
  const int k = blockIdx.y;
  const int t = threadIdx.x;
  __shared__ float fgl[16];
  const int sy = (s >> 4) * 4, sx = (s & 15) * 4;
  if (t < 16) {
    int y0 = (sy + (t >> 2)) * 8, x0 = (sx + (t & 3)) * 8;
    fgl[t] = delta[(size_t)k * 512 * 512 + (size_t)y0 * 512 + x0];
  }
  __syncthreads();
  const int h = t >> 5, d = t & 31;
  float af = 0.f, ab = 0.f;
#pragma unroll
  for (int l = 0; l < 16; ++l) {
    int pix = (sy + (l >> 2)) * 64 + sx + (l & 3);
    float sv = s_n[((size_t)k * HW + pix) * 256 + h * 32 + d];
    float f = fgl[l];
    af += f * sv;
    ab += (1.f - f) * sv;
  }
  float ssf = af * af, ssb = ab * ab;
#pragma unroll
  for (int m = 1; m <= 16; m <<= 1) {
    ssf += __shfl_xor(ssf, m);
    ssb += __shfl_xor(ssb, m);
  }
  float vf = af / fmaxf(sqrtf(ssf), 1e-12f);
  float vb = ab / fmaxf(sqrtf(ssb), 1e-12f);
  const int jf = k * 512 + s, jb = jf + 256;
  c_s[((size_t)h * 2560 + jf) * 32 + d] = vf;
  c_s[((size_t)h * 2560 + jb) * 32 + d] = vb;
  if (t == 0) {
    float fs = 0.f;
#pragma unroll
    for (int l = 0; l < 16; ++l) fs += fgl[l];
    mask[jf] = (fs < 1.f) ? -1e30f : 0.f;
    mask[jb] = ((16.f - fs) < 1.f) ? -1e30f : 0.f;
  }
}

// ---------------------------------------------------------------------------
// Attention partials: grid (16 pixel-tiles, 8 heads, 10 key-tiles), block 256.
// Each block stages 256 keys (32.8 KB LDS); thread = pixel.
// part[((z*8+h)*HW+p)*2 + {num,den}]
// ---------------------------------------------------------------------------
__global__ __launch_bounds__(256) void attn_kernel(
    const float* __restrict__ q_n, const float* __restrict__ c_s,
    const float* __restrict__ mask, float* __restrict__ part) {
  const int t = threadIdx.x;
  const int p = blockIdx.x * 256 + t;
  const int h = blockIdx.y;
  const int z = blockIdx.z;          // key tile
  __shared__ float csl[256 * 32];
  __shared__ float ml[256];
  const int j0 = z * 256;

#pragma unroll
  for (int i = 0; i < 8; ++i) {
    int idx = i * 256 + t;           // 2048 float4s = 256 keys * 8
    int key = idx >> 3, d4 = idx & 7;
    *(float4*)&csl[idx * 4] =
        *(const float4*)&c_s[((size_t)h * 2560 + j0 + key) * 32 + d4 * 4];
  }
  ml[t] = mask[j0 + t];

  float qv[32];
#pragma unroll
  for (int i = 0; i < 8; ++i) {
    float4 v = *(const float4*)&q_n[(size_t)p * 256 + h * 32 + i * 4];
    qv[i * 4 + 0] = v.x; qv[i * 4 + 1] = v.y; qv[i * 4 + 2] = v.z; qv[i * 4 + 3] = v.w;
  }
  __syncthreads();

  const float cv = ((j0 & 511) < 256) ? 1.f : 0.f;  // whole 256-tile is fg or bg
  float num = 0.f, den = 0.f;
  for (int jj = 0; jj < 256; ++jj) {
    float dot = 0.f;
#pragma unroll
    for (int i = 0; i < 8; ++i) {
      float4 c4 = *(const float4*)&csl[jj * 32 + i * 4];
      dot += qv[i * 4 + 0] * c4.x + qv[i * 4 + 1] * c4.y +
             qv[i * 4 + 2] * c4.z + qv[i * 4 + 3] * c4.w;
    }
    float e = __expf(dot + ml[jj]);   // masked -> 0
    den += e;
    num += cv * e;
  }
  float* o = &part[(((size_t)z * 8 + h) * HW + p) * 2];
  o[0] = num;
  o[1] = den;
}

// merge 10 key-tile partials: xo[h*HW+p]
__global__ __launch_bounds__(256) void merge_kernel(const float* __restrict__ part,
                                                    float* __restrict__ xo) {
  int idx = blockIdx.x * 256 + threadIdx.x;   // 32768 = h*HW+p
  int h = idx >> 12, p = idx & 4095;
  float n = 0.f, d = 0.f;
#pragma unroll
  for (int z = 0; z < 10; ++z) {
    const float* o = &part[(((size_t)z * 8 + h) * HW + p) * 2];
    n += o[0];
    d += o[1];
  }
  xo[idx] = n / d;
}

// ---------------------------------------------------------------------------
// Conv (cross-correlation) — naive; weight index uniform per block (scalarized)
// ---------------------------------------------------------------------------
template <int CI, int KS, int PAD>
__global__ __launch_bounds__(256) void n_conv(
    const float* __restrict__ in, const float* __restrict__ w,
    const float* __restrict__ b, float* __restrict__ out) {
  const int co = blockIdx.y;
  const int p = blockIdx.x * 256 + threadIdx.x;
  const int y = p >> 6, xx = p & 63;
  float acc = b[co];
  for (int ci = 0; ci < CI; ++ci)
#pragma unroll
    for (int ky = 0; ky < KS; ++ky) {
      int iy = y + ky - PAD;
      if (iy < 0 || iy >= 64) continue;
#pragma unroll
      for (int kx = 0; kx < KS; ++kx) {
        int ix = xx + kx - PAD;
        if (ix < 0 || ix >= 64) continue;
        acc += in[(size_t)ci * HW + iy * 64 + ix] *
               w[(size_t)((co * CI + ci) * KS + ky) * KS + kx];
      }
    }
  out[(size_t)co * HW + p] = acc;
}

// ---------------------------------------------------------------------------
// GroupNorm stats, two-stage: A = 16 partial blocks per group, B = finalize.
// ---------------------------------------------------------------------------
__global__ __launch_bounds__(256) void gnstatsA(const float* __restrict__ in,
                                                float* __restrict__ stp, int cpg) {
  __shared__ float sh[256], sh2[256];
  const int g = blockIdx.x, b = blockIdx.y, t = threadIdx.x;
  const int n = cpg * HW;
  const int chunk = n >> 4;
  const float* __restrict__ base = in + (size_t)g * n + (size_t)b * chunk;
  float s = 0.f, ss = 0.f;
  for (int i = t; i < chunk; i += 256) {
    float v = base[i];
    s += v;
    ss += v * v;
  }
  sh[t] = s; sh2[t] = ss;
  __syncthreads();
  for (int w = 128; w > 0; w >>= 1) {
    if (t < w) { sh[t] += sh[t + w]; sh2[t] += sh2[t + w]; }
    __syncthreads();
  }
  if (t == 0) { stp[(g * 16 + b) * 2] = sh[0]; stp[(g * 16 + b) * 2 + 1] = sh2[0]; }
}

__global__ __launch_bounds__(64) void gnstatsB(const float* __restrict__ stp,
                                               float* __restrict__ st, int cpg) {
  const int g = blockIdx.x;
  if (threadIdx.x == 0) {
    float S = 0.f, SS = 0.f;
    for (int b = 0; b < 16; ++b) { S += stp[(g * 16 + b) * 2]; SS += stp[(g * 16 + b) * 2 + 1]; }
    float n = (float)(cpg * HW);
    float mean = S / n;
    float var = SS / n - mean * mean;
    st[g * 2] = mean;
    st[g * 2 + 1] = 1.0f / sqrtf(var + 1e-5f);
  }
}

// GroupNorm apply + ReLU, float32 out (reference output dtype).
__global__ __launch_bounds__(256) void gn_apply(
    const float* __restrict__ in, float* __restrict__ out, const float* __restrict__ st,
    const float* __restrict__ gs, const float* __restrict__ gb, int cpg) {
  const int idx = blockIdx.x * 256 + threadIdx.x;
  const int c = idx >> 12;
  const int g = c / cpg;
  float v = (in[idx] - st[g * 2]) * st[g * 2 + 1] * gs[c] + gb[c];
  out[idx] = fmaxf(v, 0.f);
}

// ---------------------------------------------------------------------------
extern "C" void kernel_launch(void* const* d_in, const int* in_sizes, int n_in,
                              void* d_out, int out_size, void* d_ws, size_t ws_size,
                              hipStream_t stream) {
  const float* x     = (const float*)d_in[0];
  const float* delta = (const float*)d_in[1];
  const float* Wq    = (const float*)d_in[2];
  const float* bq    = (const float*)d_in[3];
  const float* Ws    = (const float*)d_in[4];
  const float* bs    = (const float*)d_in[5];
  const float* scale = (const float*)d_in[6];
  const float* c1w = (const float*)d_in[7],  *c1b = (const float*)d_in[8];
  const float* g1s = (const float*)d_in[9],  *g1b = (const float*)d_in[10];
  const float* c2w = (const float*)d_in[11], *c2b = (const float*)d_in[12];
  const float* g2s = (const float*)d_in[13], *g2b = (const float*)d_in[14];
  const float* c3w = (const float*)d_in[15], *c3b = (const float*)d_in[16];
  const float* g3s = (const float*)d_in[17], *g3b = (const float*)d_in[18];

  float* ws   = (float*)d_ws;
  float* q_n  = ws;                       // 1,048,576
  float* s_n  = q_n + 1048576;            // 5,242,880
  float* c_s  = s_n + 5242880;            //   655,360
  float* mask = c_s + 655360;             //     2,560
  float* xo   = mask + 2560;              //    32,768
  float* st   = xo + 32768;               //        32
  float* stp  = st + 32;                  //       512 (128 used)
  float* un   = stp + 512;                // union: part (655,360) then conv temps
  float* part = un;                       //   655,360 (10*8*4096*2)
  float* t1   = un;                       //    65,536
  float* a1   = un + 65536;               //    65,536
  float* t2   = un + 131072;              //   262,144
  float* a2   = un + 393216;              //   262,144
  float* t3   = un + 655360;              //   524,288
  // total: 6,982,720 + 1,179,648 = 8,162,368 floats ~= 32.6 MB

  proj_kernel<<<dim3(64, 6), 256, 0, stream>>>(x, Wq, bq, Ws, bs, scale, q_n, s_n);
  agg_kernel<<<dim3(256, 5), 256, 0, stream>>>(delta, s_n, c_s, mask);
  attn_kernel<<<dim3(16, 8, 10), 256, 0, stream>>>(q_n, c_s, mask, part);
  merge_kernel<<<128, 256, 0, stream>>>(part, xo);

  n_conv<8, 5, 2><<<dim3(16, 16), 256, 0, stream>>>(xo, c1w, c1b, t1);
  gnstatsA<<<dim3(4, 16), 256, 0, stream>>>(t1, stp, 4);
  gnstatsB<<<4, 64, 0, stream>>>(stp, st, 4);
  gn_apply<<<256, 256, 0, stream>>>(t1, a1, st, g1s, g1b, 4);

  n_conv<16, 3, 1><<<dim3(16, 64), 256, 0, stream>>>(a1, c2w, c2b, t2);
  gnstatsA<<<dim3(4, 16), 256, 0, stream>>>(t2, stp + 128, 16);
  gnstatsB<<<4, 64, 0, stream>>>(stp + 128, st + 8, 16);
  gn_apply<<<1024, 256, 0, stream>>>(t2, a2, st + 8, g2s, g2b, 16);

  n_conv<64, 3, 1><<<dim3(16, 128), 256, 0, stream>>>(a2, c3w, c3b, t3);
  gnstatsA<<<dim3(4, 16), 256, 0, stream>>>(t3, stp + 256, 32);
  gnstatsB<<<4, 64, 0, stream>>>(stp + 256, st + 16, 32);
  gn_apply<<<2048, 256, 0, stream>>>(t3, (float*)d_out, st + 16, g3s, g3b, 32);
}